// Round 18
// baseline (33.963 us; speedup 1.0000x reference)
//
#include <hip/hip_runtime.h>
#include <hip/hip_bf16.h>
#include <hip/hip_fp8.h>

// VQ-VAE quantize: x[32,64,64,64] NCHW fp32, codebook[512,64] fp32.
// out[0] = 1.25*SSD/8388608 ; out[1..] = codebook[argmin] in NCHW.
// R18 = R17 structure scaled to 128-row tiles (1024 blk x 256 thr x 4 waves):
// same per-wave scan, same occupancy (16 waves/CU), half the per-block fixed
// costs (staging ramp, hn2 stage, barriers, epilogue setup). All sub-patterns
// proven: fp8 B-fragments direct from L1-resident ws, unroll 2, R7 d-major
// epilogue, no cross-barrier global-load reg lifetimes, no ticket/finalize
// fusion (banned: VGPR-44 collapse, R9+R16).

typedef __attribute__((ext_vector_type(4))) float f32x4;

// ---- d_ws layout (bytes) ----
#define WS_CBF   0        // 32768: fp8 codebook B-fragments (32 ct x 2 kk x 512B)
#define WS_HN2   32768    // 2048:  (256 - 128*||c||^2) f32[512]
#define WS_RED   34816    // 16384: per-wave loss partials f32[4096]

// ---- main kernel LDS layout (bytes) ----
#define K_XA   0        // 8192:  fp8 x-tile [128 rows][64 B] swizzled
#define K_HN   8192     // 2048:  hn2' f32[512]
#define K_IDX  33792    // 512:   int idx[128]  (outside phase-B overlay)
#define K_SZ   34304
// phase-B overlay: f32 qld2[64 d][132 rows] = 33792 B over [0,33792); xa/hn dead.

__device__ __forceinline__ unsigned f2b1(float f) {
  unsigned u = __float_as_uint(f);
  return (u + 0x7FFFu + ((u >> 16) & 1)) >> 16;
}
__device__ __forceinline__ unsigned pack2(float lo, float hi) {
  return f2b1(lo) | (f2b1(hi) << 16);
}

#if defined(__has_builtin)
#  if __has_builtin(__builtin_amdgcn_cvt_pk_fp8_f32)
#    define HAVE_CVT_PK_FP8 1
#  endif
#endif
__device__ __forceinline__ unsigned cvt4_fp8(float a, float b, float c, float d) {
#ifdef HAVE_CVT_PK_FP8
  int v = __builtin_amdgcn_cvt_pk_fp8_f32(a, b, 0, false);
  v = __builtin_amdgcn_cvt_pk_fp8_f32(c, d, v, true);
  return (unsigned)v;
#else
  __hip_fp8_e4m3 fa(a), fb(b), fc(c), fd(d);
  return (unsigned)fa.__x | ((unsigned)fb.__x << 8) |
         ((unsigned)fc.__x << 16) | ((unsigned)fd.__x << 24);
#endif
}

// ====== k0: codebook -> fp8 fragment layout + hn2' (2x-wide, R17) ======
__global__ void vq_prep(const float* __restrict__ cb, char* __restrict__ ws) {
  const int gid = blockIdx.x * 64 + threadIdx.x;  // 0..1023
  const int n   = gid >> 1;                       // code 0..511
  const int kk  = gid & 1;                        // k-half
  const float4* cb4 = (const float4*)cb;
  float4 f[8];
  #pragma unroll
  for (int j = 0; j < 8; ++j) f[j] = cb4[(n << 4) + (kk << 3) + j];
  float s = 0.f;
  #pragma unroll
  for (int j = 0; j < 8; ++j)
    s += f[j].x * f[j].x + f[j].y * f[j].y + f[j].z * f[j].z + f[j].w * f[j].w;
  const float sfull = s + __shfl_xor(s, 1, 64);   // pair shares a code
  if (kk == 0)
    ((float*)(ws + WS_HN2))[n] = 256.0f - 128.0f * sfull;  // 256*(1 - c^2/2)
  const int ct = n >> 4, col = n & 15;
  #pragma unroll
  for (int g = 0; g < 4; ++g) {
    float4 a = f[g * 2], b = f[g * 2 + 1];
    uint2 u;
    u.x = cvt4_fp8(a.x * 256.f, a.y * 256.f, a.z * 256.f, a.w * 256.f);
    u.y = cvt4_fp8(b.x * 256.f, b.y * 256.f, b.z * 256.f, b.w * 256.f);
    *(uint2*)(ws + WS_CBF + (((ct << 1) + kk) << 9) + (((g << 4) | col) << 3)) = u;
  }
}

// ================= k1: argmin + loss + scatter (128-row tiles) =============
__global__ void __launch_bounds__(256, 4)
vq_main(const float* __restrict__ x, const float* __restrict__ cb,
        const char* __restrict__ wsr, float* __restrict__ out,
        float* __restrict__ wsw) {
  __shared__ __align__(16) char smem[K_SZ];
  char*  xaz  = smem + K_XA;
  float* hn2z = (float*)(smem + K_HN);
  int*   idxz = (int*)(smem + K_IDX);
  float* qld2 = (float*)smem;             // phase-B overlay [64 d][132 rows]

  const int t    = threadIdx.x;           // 0..255
  const int bid  = blockIdx.x;            // 0..1023
  const int bimg = bid >> 5;              // image 0..31
  const int hw0  = (bid & 31) << 7;       // 128-row hw tile
  const float4* xb4 = (const float4*)(x + (bimg << 18) + hw0);
  const float4* cb4 = (const float4*)cb;
  const long*   cbl = (const long*)(wsr + WS_CBF);   // fragment-linear fp8

  // ---- stage X tile: fp8 [row][64B] swizzled; 16-lane groups read 256B ----
  float xsq = 0.f;
  {
    const int q = t >> 4;                 // d-quad 0..15 (planes 4q..4q+3)
    const int c = t & 15;                 // chunk
    #pragma unroll
    for (int j = 0; j < 2; ++j) {
      const int f = c + (j << 4);         // float4-row-group 0..31
      float4 A0 = xb4[((4 * q + 0) << 10) + f];
      float4 A1 = xb4[((4 * q + 1) << 10) + f];
      float4 A2 = xb4[((4 * q + 2) << 10) + f];
      float4 A3 = xb4[((4 * q + 3) << 10) + f];
      xsq += A0.x*A0.x + A0.y*A0.y + A0.z*A0.z + A0.w*A0.w;
      xsq += A1.x*A1.x + A1.y*A1.y + A1.z*A1.z + A1.w*A1.w;
      xsq += A2.x*A2.x + A2.y*A2.y + A2.z*A2.z + A2.w*A2.w;
      xsq += A3.x*A3.x + A3.y*A3.y + A3.z*A3.z + A3.w*A3.w;
      const float* a0 = (const float*)&A0;
      const float* a1 = (const float*)&A1;
      const float* a2 = (const float*)&A2;
      const float* a3 = (const float*)&A3;
      #pragma unroll
      for (int u = 0; u < 4; ++u) {
        int r = (f << 2) + u;
        unsigned pk = cvt4_fp8(a0[u], a1[u], a2[u], a3[u]);
        *(unsigned*)(xaz + r * 64 + ((q << 2) ^ ((r & 7) << 3))) = pk;
      }
    }
  }
  // ---- hn2' from prep ----
  hn2z[t]       = ((const float*)(wsr + WS_HN2))[t];
  hn2z[t + 256] = ((const float*)(wsr + WS_HN2))[t + 256];
  __syncthreads();

  const int lane = t & 63;
  const int wid  = t >> 6;                // 0..3
  const int lrow = lane & 15;
  const int hb   = (lane >> 4) << 3;      // k-group byte offset

  // A fragments persist in regs (2 row-subtiles x 2 k-steps, 8B each)
  long af[2][2];
  #pragma unroll
  for (int s = 0; s < 2; ++s) {
    int row = (wid << 5) + (s << 4) + lrow;
    int sw = (row & 7) << 3;
    af[s][0] = *(const long*)(xaz + row * 64 + (hb ^ sw));
    af[s][1] = *(const long*)(xaz + row * 64 + ((32 | hb) ^ sw));
  }

  unsigned bestu[2][4];
  #pragma unroll
  for (int s = 0; s < 2; ++s)
    #pragma unroll
    for (int r = 0; r < 4; ++r) bestu[s][r] = 0u;   // score' > 0 always

  const unsigned tag0 = 511u - (unsigned)lrow;

  // ---- main loop: fp8 B direct from L1-resident ws ----
  #pragma unroll 2
  for (int ct = 0; ct < 32; ++ct) {
    const long b0 = cbl[(ct << 7) + lane];          // kk=0 fragment (8B)
    const long b1 = cbl[(ct << 7) + 64 + lane];     // kk=1 fragment
    const float hv = hn2z[(ct << 4) + lrow];        // 256 - 128*c^2
    const unsigned tag = tag0 - (unsigned)(ct << 4);  // 511 - nc
    #pragma unroll
    for (int s = 0; s < 2; ++s) {
      f32x4 acc = {hv, hv, hv, hv};
      acc = __builtin_amdgcn_mfma_f32_16x16x32_fp8_fp8(af[s][0], b0, acc, 0, 0, 0);
      acc = __builtin_amdgcn_mfma_f32_16x16x32_fp8_fp8(af[s][1], b1, acc, 0, 0, 0);
      #pragma unroll
      for (int r = 0; r < 4; ++r) {
        unsigned key = (__float_as_uint(acc[r]) & 0xFFFFFE00u) | tag;
        bestu[s][r] = max(bestu[s][r], key);
      }
    }
  }

  // ---- cross-lane key-max over the 16 code columns + loss partial ----
  float vsum = 0.f;
  #pragma unroll
  for (int s = 0; s < 2; ++s) {
    #pragma unroll
    for (int r = 0; r < 4; ++r) {
      unsigned k = bestu[s][r];
      #pragma unroll
      for (int m = 1; m <= 8; m <<= 1) k = max(k, (unsigned)__shfl_xor(k, m, 64));
      if (lrow == 0) {
        idxz[(wid << 5) + (s << 4) + ((lane >> 4) << 2) + r] =
            (int)(511u - (k & 511u));
        // score = score'/256 - 1
        vsum += fmaf(__uint_as_float(k & 0xFFFFFE00u), 1.0f / 256.0f, -1.0f);
      }
    }
  }
  float lacc = xsq - 2.0f * vsum;
  #pragma unroll
  for (int m = 32; m; m >>= 1) lacc += __shfl_xor(lacc, m, 64);
  if (lane == 0) wsw[(bid << 2) + wid] = lacc;
  __syncthreads();                      // idx ready; xa/hn now dead

  // ---- phase B: gather exact fp32 code rows -> d-major LDS -> NCHW store ----
  {
    const int myrow = t >> 1;           // 0..127
    const int chh   = t & 1;            // d-half
    const int myidx = idxz[myrow];
    const float4* cbr = cb4 + (myidx << 4) + (chh << 3);
    #pragma unroll
    for (int j = 0; j < 8; ++j) {
      float4 v = cbr[j];
      const int d = (chh << 5) + (j << 2);
      qld2[(d + 0) * 132 + myrow] = v.x;
      qld2[(d + 1) * 132 + myrow] = v.y;
      qld2[(d + 2) * 132 + myrow] = v.z;
      qld2[(d + 3) * 132 + myrow] = v.w;
    }
  }
  __syncthreads();
  {
    float* outq = out + 1 + (bimg << 18) + hw0;
    const int r4 = (t & 31) << 2;       // row group of 4 (float4)
    const int d0 = t >> 5;              // base d (0..7)
    #pragma unroll
    for (int i = 0; i < 8; ++i) {
      const int d = d0 + (i << 3);
      float4 v = *(const float4*)(qld2 + d * 132 + r4);   // aligned b128
      *(float4*)(outq + (d << 12) + r4) = v;              // coalesced 16B
    }
  }
}

__global__ void vq_finalize(const float* __restrict__ ws, float* __restrict__ out) {
  int t = threadIdx.x;
  __shared__ float red[4];
  float v = 0.f;
  #pragma unroll
  for (int k = 0; k < 16; ++k) v += ws[t + (k << 8)];
  #pragma unroll
  for (int m = 32; m; m >>= 1) v += __shfl_xor(v, m, 64);
  if ((t & 63) == 0) red[t >> 6] = v;
  __syncthreads();
  if (t == 0) out[0] = (red[0] + red[1] + red[2] + red[3]) * (1.25f / 8388608.0f);
}

extern "C" void kernel_launch(void* const* d_in, const int* in_sizes, int n_in,
                              void* d_out, int out_size, void* d_ws, size_t ws_size,
                              hipStream_t stream) {
  const float* x  = (const float*)d_in[0];   // 32*64*64*64 fp32 NCHW
  const float* cb = (const float*)d_in[1];   // 512*64 fp32
  float* out = (float*)d_out;                // [0]=loss, [1..]=quantized NCHW
  char*  ws  = (char*)d_ws;                  // ~51 KB used
  vq_prep<<<16, 64, 0, stream>>>(cb, ws);
  vq_main<<<1024, 256, 0, stream>>>(x, cb, ws, out, (float*)(ws + WS_RED));
  vq_finalize<<<1, 256, 0, stream>>>((float*)(ws + WS_RED), out);
}

// Round 19
// 32.957 us; speedup vs baseline: 1.0305x; 1.0305x over previous
//
#include <hip/hip_runtime.h>
#include <hip/hip_bf16.h>
#include <hip/hip_fp8.h>

// VQ-VAE quantize: x[32,64,64,64] NCHW fp32, codebook[512,64] fp32.
// out[0] = 1.25*SSD/8388608 ; out[1..] = codebook[argmin] in NCHW.
// R19 = R14 verbatim (best measured: 33.3 us). Final configuration.
// fp8-e4m3 argmin matmul: B-fragments 32 KB (L1-resident), x-tile 4 KB.
// Codebook scaled x256 into fp8 normal range; score' = 256*score; loss
// decodes score'/256 - 1. Output gathers exact fp32 codebook rows via the
// proven LDS-transpose epilogue. 2048 blocks x 128 thr, 64-row tiles.
// Session rules (hard-won): no cross-barrier global-load reg lifetimes
// (R2/R3/R5 scratch-spill); unroll 2 only (R9 regalloc collapse); no
// in-kernel finalize ticket (R9/R16 VGPR-44 collapse); codebook read
// directly from L1/L2-resident ws, never restaged mid-loop (R5).

typedef __attribute__((ext_vector_type(4))) float f32x4;

// ---- d_ws layout (bytes) ----
#define WS_CBF   0        // 32768: fp8 codebook B-fragments (32 ct x 2 kk x 512B)
#define WS_HN2   32768    // 2048:  (256 - 128*||c||^2) f32[512]
#define WS_RED   34816    // 16384: per-wave loss partials f32[4096]

// ---- main kernel LDS layout (bytes) ----
#define K_XA   0        // 4096:  fp8 x-tile [64 rows][64 B] swizzled
#define K_HN   4096     // 2048:  hn2' f32[512]
#define K_IDX  17408    // 256:   int idx[64]   (outside phase-B overlay)
#define K_SZ   17664
// phase-B overlay: f32 qld2[64 d][68 rows] = 17408 B over [0,17408); xa/hn dead.

__device__ __forceinline__ unsigned f2b1(float f) {
  unsigned u = __float_as_uint(f);
  return (u + 0x7FFFu + ((u >> 16) & 1)) >> 16;
}
__device__ __forceinline__ unsigned pack2(float lo, float hi) {
  return f2b1(lo) | (f2b1(hi) << 16);
}

#if defined(__has_builtin)
#  if __has_builtin(__builtin_amdgcn_cvt_pk_fp8_f32)
#    define HAVE_CVT_PK_FP8 1
#  endif
#endif
__device__ __forceinline__ unsigned cvt4_fp8(float a, float b, float c, float d) {
#ifdef HAVE_CVT_PK_FP8
  int v = __builtin_amdgcn_cvt_pk_fp8_f32(a, b, 0, false);
  v = __builtin_amdgcn_cvt_pk_fp8_f32(c, d, v, true);
  return (unsigned)v;
#else
  __hip_fp8_e4m3 fa(a), fb(b), fc(c), fd(d);
  return (unsigned)fa.__x | ((unsigned)fb.__x << 8) |
         ((unsigned)fc.__x << 16) | ((unsigned)fd.__x << 24);
#endif
}

// ================= k0: codebook -> fp8 fragment layout + hn2' =================
__global__ void vq_prep(const float* __restrict__ cb, char* __restrict__ ws) {
  const int n = blockIdx.x * 64 + threadIdx.x;    // code 0..511
  const float4* cb4 = (const float4*)cb;
  float4 f[16];
  #pragma unroll
  for (int j = 0; j < 16; ++j) f[j] = cb4[(n << 4) + j];
  float s = 0.f;
  #pragma unroll
  for (int j = 0; j < 16; ++j)
    s += f[j].x * f[j].x + f[j].y * f[j].y + f[j].z * f[j].z + f[j].w * f[j].w;
  ((float*)(ws + WS_HN2))[n] = 256.0f - 128.0f * s;   // 256*(1 - c^2/2)
  const int ct = n >> 4, col = n & 15;
  // B-fragment: lane = (g<<4)|col holds code ct*16+col, k = kk*32+g*8+e (8 fp8)
  #pragma unroll
  for (int kk = 0; kk < 2; ++kk) {
    #pragma unroll
    for (int g = 0; g < 4; ++g) {
      float4 a = f[kk * 8 + g * 2], b = f[kk * 8 + g * 2 + 1];
      uint2 u;
      u.x = cvt4_fp8(a.x * 256.f, a.y * 256.f, a.z * 256.f, a.w * 256.f);
      u.y = cvt4_fp8(b.x * 256.f, b.y * 256.f, b.z * 256.f, b.w * 256.f);
      *(uint2*)(ws + WS_CBF + (((ct << 1) + kk) << 9) + (((g << 4) | col) << 3)) = u;
    }
  }
}

// ================= k1: argmin + loss + scatter =================
__global__ void __launch_bounds__(128, 4)
vq_main(const float* __restrict__ x, const float* __restrict__ cb,
        const char* __restrict__ wsr, float* __restrict__ out,
        float* __restrict__ wsw) {
  __shared__ __align__(16) char smem[K_SZ];
  char*  xaz  = smem + K_XA;
  float* hn2z = (float*)(smem + K_HN);
  int*   idxz = (int*)(smem + K_IDX);
  float* qld2 = (float*)smem;             // phase-B overlay [64 d][68 rows]

  const int t    = threadIdx.x;           // 0..127
  const int bid  = blockIdx.x;            // 0..2047
  const int bimg = bid >> 6;              // image 0..31
  const int hw0  = (bid & 63) << 6;       // 64-row hw tile
  const float4* xb4 = (const float4*)(x + (bimg << 18) + hw0);
  const float4* cb4 = (const float4*)cb;
  const long*   cbl = (const long*)(wsr + WS_CBF);   // fragment-linear fp8

  // ---- stage X tile: fp8 [row][64B] swizzled; 8-lane groups read 128B ----
  float xsq = 0.f;
  {
    const int q = t >> 3;                 // d-quad 0..15 (planes 4q..4q+3)
    const int c = t & 7;                  // chunk
    #pragma unroll
    for (int j = 0; j < 2; ++j) {
      const int f = c + (j << 3);         // float4-row-group 0..15
      float4 A0 = xb4[((4 * q + 0) << 10) + f];
      float4 A1 = xb4[((4 * q + 1) << 10) + f];
      float4 A2 = xb4[((4 * q + 2) << 10) + f];
      float4 A3 = xb4[((4 * q + 3) << 10) + f];
      xsq += A0.x*A0.x + A0.y*A0.y + A0.z*A0.z + A0.w*A0.w;
      xsq += A1.x*A1.x + A1.y*A1.y + A1.z*A1.z + A1.w*A1.w;
      xsq += A2.x*A2.x + A2.y*A2.y + A2.z*A2.z + A2.w*A2.w;
      xsq += A3.x*A3.x + A3.y*A3.y + A3.z*A3.z + A3.w*A3.w;
      const float* a0 = (const float*)&A0;
      const float* a1 = (const float*)&A1;
      const float* a2 = (const float*)&A2;
      const float* a3 = (const float*)&A3;
      #pragma unroll
      for (int u = 0; u < 4; ++u) {
        int r = (f << 2) + u;
        unsigned pk = cvt4_fp8(a0[u], a1[u], a2[u], a3[u]);
        *(unsigned*)(xaz + r * 64 + ((q << 2) ^ ((r & 7) << 3))) = pk;
      }
    }
  }
  // ---- hn2' from prep ----
  #pragma unroll
  for (int i = 0; i < 4; ++i)
    hn2z[t + (i << 7)] = ((const float*)(wsr + WS_HN2))[t + (i << 7)];
  __syncthreads();

  const int lane = t & 63;
  const int wid  = t >> 6;                // 0..1
  const int lrow = lane & 15;
  const int hb   = (lane >> 4) << 3;      // k-group byte offset

  // A fragments persist in regs (2 row-subtiles x 2 k-steps, 8B each)
  long af[2][2];
  #pragma unroll
  for (int s = 0; s < 2; ++s) {
    int row = (wid << 5) + (s << 4) + lrow;
    int sw = (row & 7) << 3;
    af[s][0] = *(const long*)(xaz + row * 64 + (hb ^ sw));
    af[s][1] = *(const long*)(xaz + row * 64 + ((32 | hb) ^ sw));
  }

  unsigned bestu[2][4];
  #pragma unroll
  for (int s = 0; s < 2; ++s)
    #pragma unroll
    for (int r = 0; r < 4; ++r) bestu[s][r] = 0u;   // score' > 0 always

  const unsigned tag0 = 511u - (unsigned)lrow;

  // ---- main loop: fp8 B direct from L1-resident ws ----
  #pragma unroll 2
  for (int ct = 0; ct < 32; ++ct) {
    const long b0 = cbl[(ct << 7) + lane];          // kk=0 fragment (8B)
    const long b1 = cbl[(ct << 7) + 64 + lane];     // kk=1 fragment
    const float hv = hn2z[(ct << 4) + lrow];        // 256 - 128*c^2
    const unsigned tag = tag0 - (unsigned)(ct << 4);  // 511 - nc
    #pragma unroll
    for (int s = 0; s < 2; ++s) {
      f32x4 acc = {hv, hv, hv, hv};
      acc = __builtin_amdgcn_mfma_f32_16x16x32_fp8_fp8(af[s][0], b0, acc, 0, 0, 0);
      acc = __builtin_amdgcn_mfma_f32_16x16x32_fp8_fp8(af[s][1], b1, acc, 0, 0, 0);
      #pragma unroll
      for (int r = 0; r < 4; ++r) {
        unsigned key = (__float_as_uint(acc[r]) & 0xFFFFFE00u) | tag;
        bestu[s][r] = max(bestu[s][r], key);
      }
    }
  }

  // ---- cross-lane key-max over the 16 code columns + loss partial ----
  float vsum = 0.f;
  #pragma unroll
  for (int s = 0; s < 2; ++s) {
    #pragma unroll
    for (int r = 0; r < 4; ++r) {
      unsigned k = bestu[s][r];
      #pragma unroll
      for (int m = 1; m <= 8; m <<= 1) k = max(k, (unsigned)__shfl_xor(k, m, 64));
      if (lrow == 0) {
        idxz[(wid << 5) + (s << 4) + ((lane >> 4) << 2) + r] =
            (int)(511u - (k & 511u));
        // score = score'/256 - 1
        vsum += fmaf(__uint_as_float(k & 0xFFFFFE00u), 1.0f / 256.0f, -1.0f);
      }
    }
  }
  float lacc = xsq - 2.0f * vsum;
  #pragma unroll
  for (int m = 32; m; m >>= 1) lacc += __shfl_xor(lacc, m, 64);
  if (lane == 0) wsw[(bid << 1) + wid] = lacc;
  __syncthreads();                      // idx ready; xa/hn now dead

  // ---- phase B: gather exact fp32 code rows -> d-major LDS -> NCHW store ----
  {
    const int myrow = t >> 1;           // 0..63
    const int chh   = t & 1;            // d-half
    const int myidx = idxz[myrow];
    const float4* cbr = cb4 + (myidx << 4) + (chh << 3);
    #pragma unroll
    for (int j = 0; j < 8; ++j) {
      float4 v = cbr[j];
      const int d = (chh << 5) + (j << 2);
      qld2[(d + 0) * 68 + myrow] = v.x;
      qld2[(d + 1) * 68 + myrow] = v.y;
      qld2[(d + 2) * 68 + myrow] = v.z;
      qld2[(d + 3) * 68 + myrow] = v.w;
    }
  }
  __syncthreads();
  {
    float* outq = out + 1 + (bimg << 18) + hw0;
    const int r4 = (t & 15) << 2;       // row group of 4 (float4)
    const int d0 = t >> 4;              // base d (0..7)
    #pragma unroll
    for (int i = 0; i < 8; ++i) {
      const int d = d0 + (i << 3);
      float4 v = *(const float4*)(qld2 + d * 68 + r4);    // aligned b128
      *(float4*)(outq + (d << 12) + r4) = v;              // coalesced 16B
    }
  }
}

__global__ void vq_finalize(const float* __restrict__ ws, float* __restrict__ out) {
  int t = threadIdx.x;
  __shared__ float red[4];
  float v = 0.f;
  #pragma unroll
  for (int k = 0; k < 16; ++k) v += ws[t + (k << 8)];
  #pragma unroll
  for (int m = 32; m; m >>= 1) v += __shfl_xor(v, m, 64);
  if ((t & 63) == 0) red[t >> 6] = v;
  __syncthreads();
  if (t == 0) out[0] = (red[0] + red[1] + red[2] + red[3]) * (1.25f / 8388608.0f);
}

extern "C" void kernel_launch(void* const* d_in, const int* in_sizes, int n_in,
                              void* d_out, int out_size, void* d_ws, size_t ws_size,
                              hipStream_t stream) {
  const float* x  = (const float*)d_in[0];   // 32*64*64*64 fp32 NCHW
  const float* cb = (const float*)d_in[1];   // 512*64 fp32
  float* out = (float*)d_out;                // [0]=loss, [1..]=quantized NCHW
  char*  ws  = (char*)d_ws;                  // ~51 KB used
  vq_prep<<<8, 64, 0, stream>>>(cb, ws);
  vq_main<<<2048, 128, 0, stream>>>(x, cb, ws, out, (float*)(ws + WS_RED));
  vq_finalize<<<1, 256, 0, stream>>>((float*)(ws + WS_RED), out);
}